// Round 4
// baseline (571.032 us; speedup 1.0000x reference)
//
#include <hip/hip_runtime.h>
#include <hip/hip_bf16.h>
#include <cstdint>
#include <cmath>

typedef __bf16 bf16;
typedef __attribute__((ext_vector_type(8))) __bf16 bf16x8;
typedef __attribute__((ext_vector_type(4))) __bf16 bf16x4;
typedef __attribute__((ext_vector_type(4))) float f32x4;

#define T_SEQ   2048
#define D_MODEL 4096
#define KV_DIM  1024
#define NH      32
#define NKV     8
#define HD      128

// async global->LDS, 16B per lane; dest = wave-uniform base + lane*16 (linear)
__device__ __forceinline__ void gload16(const void* g, void* l) {
    __builtin_amdgcn_global_load_lds(
        (__attribute__((address_space(1))) void*)g,
        (__attribute__((address_space(3))) void*)l, 16, 0, 0);
}

// ---------------- fp32 -> bf16 convert (vectorized) ----------------
__global__ void cvt_f32_bf16(const float* __restrict__ in, bf16* __restrict__ out, int n) {
    int i = (blockIdx.x * 256 + threadIdx.x) * 4;
    if (i >= n) return;
    float4 v = *(const float4*)(in + i);
    bf16x4 o = { (bf16)v.x, (bf16)v.y, (bf16)v.z, (bf16)v.w };
    *(bf16x4*)(out + i) = o;
}

// -------- all-weights fp32 [R][C] -> bf16 [C][R] transpose, one launch --------
__global__ void trans_weights(const float* __restrict__ wq, const float* __restrict__ wk,
                              const float* __restrict__ wv, const float* __restrict__ wo,
                              bf16* __restrict__ wqkvt, bf16* __restrict__ wot) {
    __shared__ float tile[32][33];
    int b = blockIdx.x;
    const float* src; bf16* dst; int C;
    if (b < 16384)      { src = wq; dst = wqkvt;                           C = 4096; }
    else if (b < 20480) { src = wk; dst = wqkvt + (size_t)4096 * 4096;     C = 1024; b -= 16384; }
    else if (b < 24576) { src = wv; dst = wqkvt + (size_t)5120 * 4096;     C = 1024; b -= 20480; }
    else                { src = wo; dst = wot;                             C = 4096; b -= 24576; }
    const int R = 4096;
    int tc = C >> 5;
    int br = b / tc, bc = b % tc;
    int r0 = br << 5, c0 = bc << 5;
    int lr = threadIdx.x >> 5, lc = threadIdx.x & 31;
#pragma unroll
    for (int i = 0; i < 4; ++i)
        tile[lr + i * 8][lc] = src[(size_t)(r0 + lr + i * 8) * C + c0 + lc];
    __syncthreads();
#pragma unroll
    for (int i = 0; i < 4; ++i) {
        int oc = lr + i * 8;
        dst[(size_t)(c0 + oc) * R + r0 + lc] = (bf16)tile[lc][oc];
    }
}

// -------- bf16 [R][C] -> bf16 [C][R] transpose --------
__global__ void trans_bf16(const bf16* __restrict__ in, bf16* __restrict__ out, int R, int C) {
    __shared__ bf16 tile[32][33];
    int tc = C >> 5;
    int br = blockIdx.x / tc, bc = blockIdx.x % tc;
    int r0 = br << 5, c0 = bc << 5;
    int lr = threadIdx.x >> 5, lc = threadIdx.x & 31;
#pragma unroll
    for (int i = 0; i < 4; ++i)
        tile[lr + i * 8][lc] = in[(size_t)(r0 + lr + i * 8) * C + c0 + lc];
    __syncthreads();
#pragma unroll
    for (int i = 0; i < 4; ++i) {
        int oc = lr + i * 8;
        out[(size_t)(c0 + oc) * R + r0 + lc] = tile[lc][oc];
    }
}

// ---------------- RoPE tables ----------------
__global__ void rope_table(float* __restrict__ cosT, float* __restrict__ sinT) {
    int i = blockIdx.x * 256 + threadIdx.x;  // T_SEQ*64
    if (i >= T_SEQ * 64) return;
    int t = i >> 6, j = i & 63;
    float inv = powf(10000.0f, -(float)j / 64.0f);
    float ang = (float)t * inv;
    cosT[i] = cosf(ang);
    sinT[i] = sinf(ang);
}

// ---------------- RoPE apply (K only now), in place on bf16 [T][H*128] ----------------
__global__ void rope_apply(bf16* __restrict__ qk, const float* __restrict__ cosT,
                           const float* __restrict__ sinT, int H, int stride) {
    int i = blockIdx.x * 256 + threadIdx.x;  // T*H*64
    if (i >= T_SEQ * H * 64) return;
    int j = i & 63;
    int h = (i >> 6) % H;
    int t = i / (64 * H);
    size_t base = (size_t)t * stride + h * HD;
    float a = (float)qk[base + j];
    float b = (float)qk[base + j + 64];
    float c = cosT[t * 64 + j], s = sinT[t * 64 + j];
    qk[base + j]      = (bf16)(a * c - b * s);
    qk[base + j + 64] = (bf16)(b * c + a * s);
}

// ---------------- GEMM: C[M][N] = A[M][K] * Bt[N][K]^T  (bf16, fp32 accum) ----------------
// m97 structure + T1 XCD swizzle. MODE 0: bf16 out. MODE 1: f32 out. MODE 2: qkv split.
template <int MODE>
__global__ __launch_bounds__(256, 3) void gemm_nt(const bf16* __restrict__ A,
                                                  const bf16* __restrict__ Bt,
                                                  void* __restrict__ O0, void* __restrict__ O1,
                                                  void* __restrict__ O2,
                                                  int M, int N, int K) {
    __shared__ bf16 ldsA[128 * 64];
    __shared__ bf16 ldsB[128 * 64];
    const int tiles_n = N >> 7;
    // XCD-aware swizzle (gridDim.x % 8 == 0 for all our launches)
    const int cpx = gridDim.x >> 3;
    const int swz = (blockIdx.x & 7) * cpx + (blockIdx.x >> 3);
    const int bm = swz / tiles_n;
    const int bn = swz % tiles_n;
    const int tid = threadIdx.x;
    const int lane = tid & 63;
    const int wid = tid >> 6;
    const int wr = wid >> 1, wc = wid & 1;
    const int l16 = lane & 15, l4 = lane >> 4;
    f32x4 acc[4][4] = {};
    const size_t row0 = (size_t)bm * 128, col0 = (size_t)bn * 128;
    const bf16* Abase = A + row0 * K;
    const bf16* Bbase = Bt + col0 * K;
    const int srow = wid * 8 + (lane >> 3);   // staging row within 32-row chunk
    const int scol = (lane & 7) * 8;          // staging col (elems)

    for (int k0 = 0; k0 < K; k0 += 64) {
#pragma unroll
        for (int c = 0; c < 4; ++c) {
            int r = c * 32 + srow;
            gload16(Abase + (size_t)r * K + k0 + scol, &ldsA[(c * 32 + wid * 8) * 64]);
            gload16(Bbase + (size_t)r * K + k0 + scol, &ldsB[(c * 32 + wid * 8) * 64]);
        }
        asm volatile("s_waitcnt vmcnt(0)" ::: "memory");
        __syncthreads();
#pragma unroll
        for (int kk = 0; kk < 2; ++kk) {
            bf16x8 af[4], bfr[4];
#pragma unroll
            for (int m = 0; m < 4; ++m)
                af[m] = *(const bf16x8*)&ldsA[(wr * 64 + m * 16 + l16) * 64 + kk * 32 + l4 * 8];
#pragma unroll
            for (int n = 0; n < 4; ++n)
                bfr[n] = *(const bf16x8*)&ldsB[(wc * 64 + n * 16 + l16) * 64 + kk * 32 + l4 * 8];
#pragma unroll
            for (int m = 0; m < 4; ++m)
#pragma unroll
                for (int n = 0; n < 4; ++n)
                    acc[m][n] = __builtin_amdgcn_mfma_f32_16x16x32_bf16(af[m], bfr[n], acc[m][n], 0, 0, 0);
        }
        __syncthreads();
    }
#pragma unroll
    for (int m = 0; m < 4; ++m)
#pragma unroll
        for (int n = 0; n < 4; ++n)
#pragma unroll
            for (int r = 0; r < 4; ++r) {
                size_t row = row0 + wr * 64 + m * 16 + l4 * 4 + r;
                size_t col = col0 + wc * 64 + n * 16 + l16;
                float v = acc[m][n][r];
                if (MODE == 1) {
                    ((float*)O0)[row * N + col] = v;
                } else if (MODE == 0) {
                    ((bf16*)O0)[row * N + col] = (bf16)v;
                } else {
                    if (col < 4096)
                        ((bf16*)O0)[row * 4096 + col] = (bf16)v;
                    else if (col < 5120)
                        ((bf16*)O1)[row * 1024 + (col - 4096)] = (bf16)v;
                    else
                        ((bf16*)O2)[row * 1024 + (col - 5120)] = (bf16)v;
                }
            }
}

// ---------------- causal GQA flash attention ----------------
// Block = 4 waves = 4 Q-heads of one KV-head, 32 q-rows per wave (2x16 halves).
// K/V double-buffered in LDS: stage(t+1) issued BEFORE compute(t); one vmcnt(0)+barrier
// per tile (T3 minimum-2-phase). Q-RoPE applied in-register. Online softmax per half.
__global__ __launch_bounds__(256, 2) void flash_attn(const bf16* __restrict__ Q,
                                                     const bf16* __restrict__ Kb,
                                                     const bf16* __restrict__ Vt,
                                                     const float* __restrict__ cosT,
                                                     const float* __restrict__ sinT,
                                                     bf16* __restrict__ ctx) {
    __shared__ bf16 ldsK[2][64 * 128];   // [key][d], granule pg = g ^ (key&15)
    __shared__ bf16 ldsV[2][128 * 64];   // [d][key], granule pg = g ^ (d&7)
    __shared__ bf16 ldsP[4][16 * 72];    // per-wave P tile, padded stride 72
    const int tid = threadIdx.x, lane = tid & 63, wid = tid >> 6;
    const int l16 = lane & 15, l4 = lane >> 4;
    const int kvh = blockIdx.x & 7;
    const int i = blockIdx.x >> 3;                 // 0..63
    const int chunk = (i < 32) ? (63 - i) : (i - 32);  // long-first, CU pairs sum ~const
    const int q0 = chunk * 32;
    const int h = kvh * 4 + wid;

    // ---- Q load + in-register RoPE: pairs (j, j+64) are (kk, kk+2) in same lane ----
    bf16x8 qf[2][4];
#pragma unroll
    for (int hh = 0; hh < 2; ++hh) {
        const int trow = q0 + hh * 16 + l16;
        const bf16* qb = Q + (size_t)trow * D_MODEL + h * HD;
        bf16x8 raw[4];
#pragma unroll
        for (int kk = 0; kk < 4; ++kk)
            raw[kk] = *(const bf16x8*)(qb + kk * 32 + l4 * 8);
#pragma unroll
        for (int kk = 0; kk < 2; ++kk) {
            const float* cb = cosT + trow * 64 + kk * 32 + l4 * 8;
            const float* sb = sinT + trow * 64 + kk * 32 + l4 * 8;
            f32x4 c0 = *(const f32x4*)cb, c1 = *(const f32x4*)(cb + 4);
            f32x4 s0 = *(const f32x4*)sb, s1 = *(const f32x4*)(sb + 4);
#pragma unroll
            for (int e = 0; e < 8; ++e) {
                float c = (e < 4) ? c0[e] : c1[e - 4];
                float s = (e < 4) ? s0[e] : s1[e - 4];
                float a = (float)raw[kk][e], b = (float)raw[kk + 2][e];
                qf[hh][kk][e]     = (bf16)(a * c - b * s);
                qf[hh][kk + 2][e] = (bf16)(b * c + a * s);
            }
        }
    }

    f32x4 acc[2][8] = {};
    float m_r[2][4], l_r[2][4];
#pragma unroll
    for (int hh = 0; hh < 2; ++hh)
#pragma unroll
        for (int r = 0; r < 4; ++r) { m_r[hh][r] = -INFINITY; l_r[hh][r] = 0.f; }
    const float scale = 0.08838834764831845f;  // 1/sqrt(128)
    bf16* Pw = ldsP[wid];
    const int nt = (q0 >> 6) + 1;

    const int krow = lane >> 4, kpg = lane & 15;
    const int vrow = lane >> 3, vpg = lane & 7;
    auto stage = [&](int buf, int t) {
        const int k0s = t * 64;
#pragma unroll
        for (int c = 0; c < 4; ++c) {
            int r = c * 16 + wid * 4 + krow;
            int g = kpg ^ (r & 15);
            gload16(Kb + (size_t)(k0s + r) * KV_DIM + kvh * HD + g * 8,
                    &ldsK[buf][(c * 16 + wid * 4) * 128]);
        }
#pragma unroll
        for (int c = 0; c < 4; ++c) {
            int r = c * 32 + wid * 8 + vrow;
            int g = vpg ^ (r & 7);
            gload16(Vt + (size_t)(kvh * 128 + r) * T_SEQ + k0s + g * 8,
                    &ldsV[buf][(c * 32 + wid * 8) * 64]);
        }
    };

    // prologue: stage tile 0
    stage(0, 0);
    asm volatile("s_waitcnt vmcnt(0)" ::: "memory");
    __syncthreads();

    for (int t = 0; t < nt; ++t) {
        const int cur = t & 1;
        const int k0 = t * 64;
        if (t + 1 < nt) stage(cur ^ 1, t + 1);  // overlaps entire tile compute

        // ---- QK^T, both q-halves share each K fragment ----
        f32x4 s[2][4] = {};
        const bf16* Kl = ldsK[cur];
        __builtin_amdgcn_s_setprio(1);
#pragma unroll
        for (int n = 0; n < 4; ++n) {
            int r = n * 16 + l16;
#pragma unroll
            for (int kk = 0; kk < 4; ++kk) {
                int pg = (kk * 4 + l4) ^ (r & 15);
                bf16x8 kf = *(const bf16x8*)&Kl[r * 128 + pg * 8];
                s[0][n] = __builtin_amdgcn_mfma_f32_16x16x32_bf16(qf[0][kk], kf, s[0][n], 0, 0, 0);
                s[1][n] = __builtin_amdgcn_mfma_f32_16x16x32_bf16(qf[1][kk], kf, s[1][n], 0, 0, 0);
            }
        }
        __builtin_amdgcn_s_setprio(0);

        // ---- scale + causal mask + online softmax (per half) ----
#pragma unroll
        for (int hh = 0; hh < 2; ++hh) {
#pragma unroll
            for (int n = 0; n < 4; ++n)
#pragma unroll
                for (int r = 0; r < 4; ++r) {
                    int key = k0 + n * 16 + l16;
                    int row = q0 + hh * 16 + l4 * 4 + r;
                    float sv = s[hh][n][r] * scale;
                    s[hh][n][r] = (key > row) ? -INFINITY : sv;
                }
            float f[4];
#pragma unroll
            for (int r = 0; r < 4; ++r) {
                float v = fmaxf(fmaxf(s[hh][0][r], s[hh][1][r]), fmaxf(s[hh][2][r], s[hh][3][r]));
                v = fmaxf(v, __shfl_xor(v, 1));
                v = fmaxf(v, __shfl_xor(v, 2));
                v = fmaxf(v, __shfl_xor(v, 4));
                v = fmaxf(v, __shfl_xor(v, 8));
                float mn = fmaxf(m_r[hh][r], v);
                f[r] = __expf(m_r[hh][r] - mn);
                m_r[hh][r] = mn;
            }
#pragma unroll
            for (int n = 0; n < 4; ++n)
#pragma unroll
                for (int r = 0; r < 4; ++r)
                    s[hh][n][r] = __expf(s[hh][n][r] - m_r[hh][r]);
#pragma unroll
            for (int r = 0; r < 4; ++r) {
                float ps = (s[hh][0][r] + s[hh][1][r]) + (s[hh][2][r] + s[hh][3][r]);
                ps += __shfl_xor(ps, 1);
                ps += __shfl_xor(ps, 2);
                ps += __shfl_xor(ps, 4);
                ps += __shfl_xor(ps, 8);
                l_r[hh][r] = l_r[hh][r] * f[r] + ps;
            }
#pragma unroll
            for (int n = 0; n < 8; ++n)
#pragma unroll
                for (int r = 0; r < 4; ++r)
                    acc[hh][n][r] *= f[r];
        }

        // ---- P -> LDS -> A-fragments (per-wave region; same-wave in-order DS) ----
        bf16x8 pf[2][2];
#pragma unroll
        for (int hh = 0; hh < 2; ++hh) {
#pragma unroll
            for (int n = 0; n < 4; ++n)
#pragma unroll
                for (int r = 0; r < 4; ++r)
                    Pw[(l4 * 4 + r) * 72 + n * 16 + l16] = (bf16)s[hh][n][r];
            pf[hh][0] = *(const bf16x8*)&Pw[l16 * 72 + l4 * 8];
            pf[hh][1] = *(const bf16x8*)&Pw[l16 * 72 + 32 + l4 * 8];
        }

        // ---- PV, both halves share each V fragment ----
        const bf16* Vl = ldsV[cur];
        __builtin_amdgcn_s_setprio(1);
#pragma unroll
        for (int n = 0; n < 8; ++n) {
            int r = n * 16 + l16;
            int pg0 = l4 ^ (r & 7);
            int pg1 = (4 + l4) ^ (r & 7);
            bf16x8 v0 = *(const bf16x8*)&Vl[r * 64 + pg0 * 8];
            bf16x8 v1 = *(const bf16x8*)&Vl[r * 64 + pg1 * 8];
            acc[0][n] = __builtin_amdgcn_mfma_f32_16x16x32_bf16(pf[0][0], v0, acc[0][n], 0, 0, 0);
            acc[0][n] = __builtin_amdgcn_mfma_f32_16x16x32_bf16(pf[0][1], v1, acc[0][n], 0, 0, 0);
            acc[1][n] = __builtin_amdgcn_mfma_f32_16x16x32_bf16(pf[1][0], v0, acc[1][n], 0, 0, 0);
            acc[1][n] = __builtin_amdgcn_mfma_f32_16x16x32_bf16(pf[1][1], v1, acc[1][n], 0, 0, 0);
        }
        __builtin_amdgcn_s_setprio(0);

        // staged tile t+1 fully landed + all waves done reading buf[cur]
        asm volatile("s_waitcnt vmcnt(0)" ::: "memory");
        __syncthreads();
    }

#pragma unroll
    for (int hh = 0; hh < 2; ++hh)
#pragma unroll
        for (int n = 0; n < 8; ++n)
#pragma unroll
            for (int r = 0; r < 4; ++r) {
                int row = q0 + hh * 16 + l4 * 4 + r;
                ctx[(size_t)row * D_MODEL + h * HD + n * 16 + l16] =
                    (bf16)(acc[hh][n][r] / l_r[hh][r]);
            }
}

// ---------------- host ----------------
extern "C" void kernel_launch(void* const* d_in, const int* in_sizes, int n_in,
                              void* d_out, int out_size, void* d_ws, size_t ws_size,
                              hipStream_t stream) {
    const float* x  = (const float*)d_in[0];
    const float* wq = (const float*)d_in[1];
    const float* wk = (const float*)d_in[2];
    const float* wv = (const float*)d_in[3];
    const float* wo = (const float*)d_in[4];
    float* out = (float*)d_out;

    char* ws = (char*)d_ws;
    size_t off = 0;
    auto alloc = [&](size_t bytes) {
        void* p = ws + off;
        off += (bytes + 255) & ~(size_t)255;
        return p;
    };
    bf16* xb    = (bf16*)alloc((size_t)T_SEQ * D_MODEL * 2);
    bf16* wqkvt = (bf16*)alloc((size_t)(D_MODEL + 2 * KV_DIM) * D_MODEL * 2);  // [6144][4096]
    bf16* wot   = (bf16*)alloc((size_t)D_MODEL * D_MODEL * 2);
    bf16* q     = (bf16*)alloc((size_t)T_SEQ * D_MODEL * 2);
    bf16* k     = (bf16*)alloc((size_t)T_SEQ * KV_DIM * 2);
    bf16* v     = (bf16*)alloc((size_t)T_SEQ * KV_DIM * 2);
    bf16* vt    = (bf16*)alloc((size_t)KV_DIM * T_SEQ * 2);
    bf16* ctx   = (bf16*)alloc((size_t)T_SEQ * D_MODEL * 2);
    float* cosT = (float*)alloc((size_t)T_SEQ * 64 * 4);
    float* sinT = (float*)alloc((size_t)T_SEQ * 64 * 4);

    // input convert + all weight transposes (one launch) + tables
    cvt_f32_bf16<<<(T_SEQ * D_MODEL) / 1024, 256, 0, stream>>>(x, xb, T_SEQ * D_MODEL);
    trans_weights<<<40960, 256, 0, stream>>>(wq, wk, wv, wo, wqkvt, wot);
    rope_table<<<(T_SEQ * 64) / 256, 256, 0, stream>>>(cosT, sinT);

    // fused QKV projection: [2048][4096] x [6144][4096]^T
    gemm_nt<2><<<(T_SEQ / 128) * ((D_MODEL + 2 * KV_DIM) / 128), 256, 0, stream>>>(
        xb, wqkvt, q, k, v, T_SEQ, D_MODEL + 2 * KV_DIM, D_MODEL);

    // RoPE on K only (Q-RoPE fused into flash)
    rope_apply<<<(T_SEQ * NKV * 64) / 256, 256, 0, stream>>>(k, cosT, sinT, NKV, KV_DIM);

    // V^T per kv-head: [2048][1024] -> [1024][2048]
    trans_bf16<<<(T_SEQ / 32) * (KV_DIM / 32), 256, 0, stream>>>(v, vt, T_SEQ, KV_DIM);

    // flash attention: 8 kv-heads x 64 q-chunks of 32 rows
    flash_attn<<<512, 256, 0, stream>>>(q, k, vt, cosT, sinT, ctx);

    // out projection (fp32 out)
    gemm_nt<1><<<(T_SEQ / 128) * (D_MODEL / 128), 256, 0, stream>>>(
        ctx, wot, out, nullptr, nullptr, T_SEQ, D_MODEL, D_MODEL);
}